// Round 3
// baseline (299.902 us; speedup 1.0000x reference)
//
#include <hip/hip_runtime.h>

#define C_CH 128
#define HW 128
#define NW (25 * C_CH + C_CH)   // 3328 weights per sample

// LDS-free row-streaming depthwise 5x5 + bias + SiLU.
// Thread = 4 output cols (j0=4*colg) x 16 output rows (strip).
// 5 rotating accumulator rows; each input row loaded once (4x float2, 8B aligned).
__global__ __launch_bounds__(256, 8) void hyperconv_dw_silu(
    const float* __restrict__ inp, const float* __restrict__ wts,
    float* __restrict__ out)
{
    const int tid   = threadIdx.x;
    const int colg  = tid & 31;    // 32 col groups of 4
    const int strip = tid >> 5;    // 8 strips of 16 rows
    const int c     = blockIdx.x;
    const int b     = blockIdx.y;

    // Block-uniform weights -> scalar loads / SGPRs
    const float* wt = wts + (size_t)b * NW + c * 25;
    float wk[25];
    #pragma unroll
    for (int j = 0; j < 25; ++j) wk[j] = wt[j];
    const float bias = wts[(size_t)b * NW + 25 * C_CH + c];

    const float* plane  = inp + ((size_t)(b * C_CH + c)) * (HW * HW);
    float*       oplane = out + ((size_t)(b * C_CH + c)) * (HW * HW);

    const int R0 = strip * 16;   // first output row of this thread
    const int j0 = colg * 4;     // first output col

    float acc[5][4];
    #pragma unroll
    for (int s = 0; s < 5; ++s)
        #pragma unroll
        for (int oc = 0; oc < 4; ++oc) acc[s][oc] = bias;

    const bool haveL = (colg > 0);    // cols j0-2,j0-1 exist in-row
    const bool haveR = (colg < 31);   // cols j0+4,j0+5 exist in-row

    #pragma unroll
    for (int ir = 0; ir < 20; ++ir) {             // input rows R0-2 .. R0+17
        const int gr = R0 - 2 + ir;
        const bool vr = (unsigned)gr < (unsigned)HW;
        const float* rp = plane + (size_t)(vr ? gr : 0) * HW + j0;

        // x[0..7] = input cols j0-2 .. j0+5 (zeros outside the image)
        float2 A  = (vr && haveL) ? *(const float2*)(rp - 2) : make_float2(0.f, 0.f);
        float2 Bq = vr            ? *(const float2*)(rp    ) : make_float2(0.f, 0.f);
        float2 Cq = vr            ? *(const float2*)(rp + 2) : make_float2(0.f, 0.f);
        float2 D  = (vr && haveR) ? *(const float2*)(rp + 4) : make_float2(0.f, 0.f);
        float x[8] = {A.x, A.y, Bq.x, Bq.y, Cq.x, Cq.y, D.x, D.y};

        // scatter this input row into the (up to 5) pending output rows
        #pragma unroll
        for (int kh = 0; kh < 5; ++kh) {
            const int k = ir - kh;                // output row index (rel)
            if (k < 0 || k > 15) continue;        // compile-time resolved
            const int s = k % 5;
            #pragma unroll
            for (int oc = 0; oc < 4; ++oc)
                #pragma unroll
                for (int kw = 0; kw < 5; ++kw)
                    acc[s][oc] = fmaf(wk[kh * 5 + kw], x[oc + kw], acc[s][oc]);
        }

        // output row k = ir-4 is now complete: SiLU + store, recycle slot
        if (ir >= 4) {
            const int k = ir - 4;
            const int s = k % 5;
            float4 o;
            float* po = (float*)&o;
            #pragma unroll
            for (int oc = 0; oc < 4; ++oc) {
                const float v = acc[s][oc];
                const float t = __builtin_amdgcn_exp2f(v * -1.44269504088896341f);
                po[oc] = v * __builtin_amdgcn_rcpf(1.0f + t);
            }
            *(float4*)(oplane + (size_t)(R0 + k) * HW + j0) = o;
            #pragma unroll
            for (int oc = 0; oc < 4; ++oc) acc[s][oc] = bias;   // row k+5
        }
    }
}

extern "C" void kernel_launch(void* const* d_in, const int* in_sizes, int n_in,
                              void* d_out, int out_size, void* d_ws, size_t ws_size,
                              hipStream_t stream) {
    const float* inp = (const float*)d_in[0];
    const float* wts = (const float*)d_in[1];
    float* out = (float*)d_out;

    const int batch = in_sizes[1] / NW;   // 16
    dim3 grid(C_CH, batch);               // one block per (b,c) plane
    hyperconv_dw_silu<<<grid, 256, 0, stream>>>(inp, wts, out);
}